// Round 4
// baseline (511.211 us; speedup 1.0000x reference)
//
#include <hip/hip_runtime.h>
#include <cstdint>
#include <cstddef>

// Out[M][N] = X[M][K] @ W[N][K]^T + bias[N].  f32 storage, bf16 MFMA compute.
#define M_DIM 8192
#define N_DIM 4096
#define K_DIM 4096

typedef __bf16 bf16x8 __attribute__((ext_vector_type(8)));
typedef float  f32x4  __attribute__((ext_vector_type(4)));
typedef float  f32x16 __attribute__((ext_vector_type(16)));
typedef unsigned short u16x4 __attribute__((ext_vector_type(4)));
typedef unsigned short u16x8 __attribute__((ext_vector_type(8)));

__device__ __forceinline__ unsigned short f32_to_bf16(float f) {
    unsigned int v = __builtin_bit_cast(unsigned int, f);
    v += 0x7FFFu + ((v >> 16) & 1u);   // round-to-nearest-even
    return (unsigned short)(v >> 16);
}

__device__ __forceinline__ void load16_lds(const void* g, void* l) {
    __builtin_amdgcn_global_load_lds(
        (__attribute__((address_space(1))) void*)(g),
        (__attribute__((address_space(3))) void*)(l),
        16, 0, 0);
}

// All carry "memory" clobbers: no memory op may be compiler-moved across.
#define VMCNT(n) asm volatile("s_waitcnt vmcnt(" #n ")" ::: "memory")
#define BAR()    asm volatile("s_barrier" ::: "memory")

// ---------- pre-pass: f32 -> bf16 (RNE), MLP=8 restructure ----------
// R3 post-mortem: the old loop was LATENCY-bound (~1.2 TB/s): one dependent
// load->cvt->store chain per grid-stride iter = ~2 loads in flight/wave.
// 32 waves/CU x 64B / 900cy x 256CU = 1.4 TB/s — matched. Fix: 4 independent
// chunks, all 8 dwordx4 loads issued before any convert/store.
__global__ __launch_bounds__(256) void cvt_f32_to_bf16_2(
    const float* __restrict__ X, const float* __restrict__ W,
    unsigned short* __restrict__ dX, unsigned short* __restrict__ dW,
    int nX8, int nTot8) {
    const int stride = gridDim.x * blockDim.x;
    int i0 = blockIdx.x * blockDim.x + threadIdx.x;
    for (; i0 < nTot8; i0 += 4 * stride) {
        f32x4 a[4], b[4];
        #pragma unroll
        for (int c = 0; c < 4; ++c) {
            const int i = i0 + c * stride;
            if (i < nTot8) {
                const float* s = (i < nX8) ? X + (size_t)i * 8
                                           : W + (size_t)(i - nX8) * 8;
                a[c] = *(const f32x4*)(s);
                b[c] = *(const f32x4*)(s + 4);
            }
        }
        #pragma unroll
        for (int c = 0; c < 4; ++c) {
            const int i = i0 + c * stride;
            if (i < nTot8) {
                unsigned short* d = (i < nX8) ? dX + (size_t)i * 8
                                              : dW + (size_t)(i - nX8) * 8;
                u16x8 o;
                o[0] = f32_to_bf16(a[c].x); o[1] = f32_to_bf16(a[c].y);
                o[2] = f32_to_bf16(a[c].z); o[3] = f32_to_bf16(a[c].w);
                o[4] = f32_to_bf16(b[c].x); o[5] = f32_to_bf16(b[c].y);
                o[6] = f32_to_bf16(b[c].z); o[7] = f32_to_bf16(b[c].w);
                *(u16x8*)d = o;
            }
        }
    }
}

// ---------- main GEMM: 256x256 tile, BK=32 slices, 4-deep LDS ring ----------
// R4: 32x32x16 MFMA (2495 TF ceiling vs ~2100 for 16x16, m119/m06).
// 512 threads = 8 waves (2M x 4N), per-wave 128x64 = 4x2 tiles of 32x32.
// Same 12 ds_read_b128/slice, but 16 MFMA (8.07cy) vs 32 (4.85cy):
// per-CU slice floor 1242 -> 1033 cyc. Schedule/ring/swizzle from R3
// (measured: 0 bank conflicts, race-free vmcnt accounting) unchanged.
// 32-row frag reads under the same XOR swizzle stay bank-balanced: each
// group of 8 consecutive lanes hits 8 distinct bank-quads.
__global__ __launch_bounds__(512, 2) void gemm_256_pipe(
    const unsigned short* __restrict__ X,    // [M][K] bf16 (ws)
    const unsigned short* __restrict__ W,    // [N][K] bf16 (ws)
    const float* __restrict__ Bias,          // [N] f32
    float* __restrict__ Out)                 // [M][N] f32
{
    __shared__ alignas(16) unsigned short ldsA[4][8192];   // [buf][256*32]
    __shared__ alignas(16) unsigned short ldsB[4][8192];

    const int tid  = threadIdx.x;
    const int wave = tid >> 6;
    const int lane = tid & 63;

    // T1: XCD-aware bijective swizzle. 512 wgs, 8 XCDs, 64 wgs/XCD chunk.
    const int bid = blockIdx.x;
    const int wg  = (bid & 7) * 64 + (bid >> 3);
    const int tileM = (wg >> 4) * 256;     // 32 tile-rows
    const int tileN = (wg & 15) * 256;     // 16 tile-cols

    // ---- staging addresses (per-thread, pre-swizzled global source) ----
    const int row4 = tid >> 2;                                  // 0..127
    const int swzc = (((tid & 3) ^ ((tid >> 3) & 3)) << 3);     // elems
    const unsigned short* gA0 = X + (size_t)(tileM + row4) * K_DIM + swzc;
    const unsigned short* gA1 = gA0 + (size_t)128 * K_DIM;
    const unsigned short* gB0 = W + (size_t)(tileN + row4) * K_DIM + swzc;
    const unsigned short* gB1 = gB0 + (size_t)128 * K_DIM;

    // ---- fragment read bases (32x32x16: row = lane&31, kchunk = lane>>5) --
    const int lr = lane & 31;
    const int hi = lane >> 5;
    const int wm = wave >> 2;   // 0..1
    const int wn = wave & 3;    // 0..3
    const int swz = (lr >> 1) & 3;
    const int kpos0 = ((0 + hi) ^ swz) << 3;   // ks=0: logical chunk hi
    const int kpos1 = ((2 + hi) ^ swz) << 3;   // ks=1: logical chunk 2+hi
    const unsigned short* aB0 = &ldsA[0][(wm * 128 + lr) * 32 + kpos0];
    const unsigned short* aB1 = &ldsA[0][(wm * 128 + lr) * 32 + kpos1];
    const unsigned short* bB0 = &ldsB[0][(wn * 64  + lr) * 32 + kpos0];
    const unsigned short* bB1 = &ldsB[0][(wn * 64  + lr) * 32 + kpos1];

    f32x16 acc[4][2];
    #pragma unroll
    for (int i = 0; i < 4; ++i)
        #pragma unroll
        for (int j = 0; j < 2; ++j)
            #pragma unroll
            for (int e = 0; e < 16; ++e)
                acc[i][j][e] = 0.f;

#define STAGE(s, b) do {                                        \
        const int ko_ = (s) * 32;                               \
        load16_lds(gA0 + ko_, &ldsA[b][       wave * 512]);     \
        load16_lds(gA1 + ko_, &ldsA[b][4096 + wave * 512]);     \
        load16_lds(gB0 + ko_, &ldsB[b][       wave * 512]);     \
        load16_lds(gB1 + ko_, &ldsB[b][4096 + wave * 512]);     \
    } while (0)

    // one pipelined slice: reads -> sync/stage window -> MFMA cluster
#define SLICE_PIPE(b, do_stage, ss, sb, vm) do {                \
        const unsigned short* pa0_ = aB0 + (b) * 8192;          \
        const unsigned short* pa1_ = aB1 + (b) * 8192;          \
        const unsigned short* pb0_ = bB0 + (b) * 8192;          \
        const unsigned short* pb1_ = bB1 + (b) * 8192;          \
        bf16x8 af[4][2]; bf16x8 bv[2][2];                       \
        _Pragma("unroll")                                       \
        for (int mb = 0; mb < 4; ++mb) {                        \
            af[mb][0] = *(const bf16x8*)(pa0_ + mb * 1024);     \
            af[mb][1] = *(const bf16x8*)(pa1_ + mb * 1024);     \
        }                                                       \
        _Pragma("unroll")                                       \
        for (int nb = 0; nb < 2; ++nb) {                        \
            bv[nb][0] = *(const bf16x8*)(pb0_ + nb * 1024);     \
            bv[nb][1] = *(const bf16x8*)(pb1_ + nb * 1024);     \
        }                                                       \
        VMCNT(vm);                                              \
        BAR();                                                  \
        if (do_stage) STAGE(ss, sb);                            \
        __builtin_amdgcn_sched_barrier(0);                      \
        __builtin_amdgcn_s_setprio(1);                          \
        _Pragma("unroll")                                       \
        for (int ks = 0; ks < 2; ++ks)                          \
            _Pragma("unroll")                                   \
            for (int mb = 0; mb < 4; ++mb)                      \
                _Pragma("unroll")                               \
                for (int nb = 0; nb < 2; ++nb)                  \
                    acc[mb][nb] = __builtin_amdgcn_mfma_f32_32x32x16_bf16( \
                        af[mb][ks], bv[nb][ks], acc[mb][nb], 0, 0, 0);     \
        __builtin_amdgcn_s_setprio(0);                          \
    } while (0)

    // ---- prologue: stage slices 0,1,2; retire slice 0 ----
    STAGE(0, 0); STAGE(1, 1); STAGE(2, 2);
    VMCNT(8);           // 12 outstanding -> retire slice 0
    BAR();

    // ---- main loop: slices 0..123 (stage t+3 = 3..126) ----
    #pragma unroll 1
    for (int t4 = 0; t4 < 124; t4 += 4) {
        SLICE_PIPE(0, true, t4 + 3, 3, 4);
        SLICE_PIPE(1, true, t4 + 4, 0, 4);
        SLICE_PIPE(2, true, t4 + 5, 1, 4);
        SLICE_PIPE(3, true, t4 + 6, 2, 4);
    }
    // ---- tail: slices 124..127 ----
    SLICE_PIPE(0, true, 127, 3, 4);   // t=124: retire 125, stage 127
    SLICE_PIPE(1, false, 0, 0, 4);    // t=125: retire 126 ({126,127} out)
    SLICE_PIPE(2, false, 0, 0, 0);    // t=126: retire 127
    SLICE_PIPE(3, false, 0, 0, 63);   // t=127: no wait needed (vmcnt 63 = nop)

#undef STAGE
#undef SLICE_PIPE

    // ---- C write + bias (32x32 C layout: col=lane&31,
    //      row = (reg&3) + 8*(reg>>2) + 4*(lane>>5), m74/m101) ----
    #pragma unroll
    for (int nb = 0; nb < 2; ++nb) {
        const int col = tileN + wn * 64 + nb * 32 + lr;
        const float bvl = Bias[col];
        #pragma unroll
        for (int mb = 0; mb < 4; ++mb) {
            #pragma unroll
            for (int q = 0; q < 4; ++q) {
                const int rowb = tileM + wm * 128 + mb * 32 + q * 8 + hi * 4;
                #pragma unroll
                for (int r = 0; r < 4; ++r)
                    Out[(size_t)(rowb + r) * N_DIM + col] = acc[mb][nb][q * 4 + r] + bvl;
            }
        }
    }
}

// ---------- fallback GEMM (ws too small): f32 load + cvt during staging ----
__global__ __launch_bounds__(256, 3) void gemm_bt_reg(
    const float* __restrict__ X,    // [M][K] f32
    const float* __restrict__ W,    // [N][K] f32
    const float* __restrict__ Bias,
    float* __restrict__ Out)
{
    __shared__ alignas(16) unsigned short sA[2][128][32];
    __shared__ alignas(16) unsigned short sB[2][128][32];

    const int tid  = threadIdx.x;
    const int wave = tid >> 6;
    const int lane = tid & 63;
    const int tileM = blockIdx.x * 128;
    const int tileN = blockIdx.y * 128;

    const int fr = lane & 15;
    const int fq = lane >> 4;
    const int wm = (wave >> 1) * 64;
    const int wn = (wave & 1) * 64;

    f32x4 acc[4][4];
    #pragma unroll
    for (int i = 0; i < 4; ++i)
        #pragma unroll
        for (int j = 0; j < 4; ++j)
            acc[i][j] = f32x4{0.f, 0.f, 0.f, 0.f};

    for (int k0 = 0; k0 < K_DIM; k0 += 64) {
        __syncthreads();
        #pragma unroll
        for (int ks = 0; ks < 2; ++ks) {
            #pragma unroll
            for (int jj = 0; jj < 4; ++jj) {
                const int f   = tid + jj * 256;   // 0..1023
                const int row = f >> 3;
                const int c4  = (f & 7) * 4;
                f32x4 va = *(const f32x4*)(X + (size_t)(tileM + row) * K_DIM + k0 + ks * 32 + c4);
                f32x4 vb = *(const f32x4*)(W + (size_t)(tileN + row) * K_DIM + k0 + ks * 32 + c4);
                u16x4 oa, ob;
                oa.x = f32_to_bf16(va.x); oa.y = f32_to_bf16(va.y);
                oa.z = f32_to_bf16(va.z); oa.w = f32_to_bf16(va.w);
                ob.x = f32_to_bf16(vb.x); ob.y = f32_to_bf16(vb.y);
                ob.z = f32_to_bf16(vb.z); ob.w = f32_to_bf16(vb.w);
                *(u16x4*)&sA[ks][row][c4] = oa;
                *(u16x4*)&sB[ks][row][c4] = ob;
            }
        }
        __syncthreads();

        #pragma unroll
        for (int ks = 0; ks < 2; ++ks) {
            bf16x8 af[4], bfr[4];
            #pragma unroll
            for (int i = 0; i < 4; ++i) {
                af[i]  = *(const bf16x8*)&sA[ks][wm + i * 16 + fr][fq * 8];
                bfr[i] = *(const bf16x8*)&sB[ks][wn + i * 16 + fr][fq * 8];
            }
            #pragma unroll
            for (int i = 0; i < 4; ++i)
                #pragma unroll
                for (int j = 0; j < 4; ++j)
                    acc[i][j] = __builtin_amdgcn_mfma_f32_16x16x32_bf16(
                        af[i], bfr[j], acc[i][j], 0, 0, 0);
        }
    }

    #pragma unroll
    for (int j = 0; j < 4; ++j) {
        const int col = tileN + wn + j * 16 + fr;
        const float bv = Bias[col];
        #pragma unroll
        for (int i = 0; i < 4; ++i) {
            const int rowb = tileM + wm + i * 16 + fq * 4;
            f32x4 v = acc[i][j];
            #pragma unroll
            for (int r = 0; r < 4; ++r)
                Out[(size_t)(rowb + r) * N_DIM + col] = v[r] + bv;
        }
    }
}

extern "C" void kernel_launch(void* const* d_in, const int* in_sizes, int n_in,
                              void* d_out, int out_size, void* d_ws, size_t ws_size,
                              hipStream_t stream) {
    const float* X    = (const float*)d_in[0];  // [8192][4096]
    const float* W    = (const float*)d_in[1];  // [4096][4096]
    const float* Bias = (const float*)d_in[2];  // [4096]
    float* Out = (float*)d_out;

    const size_t nX = (size_t)M_DIM * K_DIM;          // 33554432
    const size_t nW = (size_t)N_DIM * K_DIM;          // 16777216
    const size_t need = (nX + nW) * sizeof(unsigned short);  // ~96 MB

    if (ws_size >= need) {
        unsigned short* wsX = (unsigned short*)d_ws;
        unsigned short* wsW = wsX + nX;
        const int nX8   = (int)(nX / 8);
        const int nTot8 = (int)((nX + nW) / 8);
        cvt_f32_to_bf16_2<<<2048, 256, 0, stream>>>(X, W, wsX, wsW, nX8, nTot8);
        gemm_256_pipe<<<dim3(512), dim3(512), 0, stream>>>(wsX, wsW, Bias, Out);
    } else {
        dim3 grid(M_DIM / 128, N_DIM / 128);
        gemm_bt_reg<<<grid, dim3(256), 0, stream>>>(X, W, Bias, Out);
    }
}